// Round 1
// baseline (1780.748 us; speedup 1.0000x reference)
//
#include <hip/hip_runtime.h>
#include <math.h>

#define FIN   128
#define C     128      // NH*FOUT
#define NHH   4
#define FOUTD 32
#define NNODE 50000
#define NEDGE 800000

__device__ __forceinline__ float lrelu(float x) { return x > 0.f ? x : 0.2f * x; }

// ---------------------------------------------------------------------------
// Projection + fused per-node score: proj = X @ W  (N x 128 @ 128 x 128)
// scores[n][h] = sum_f proj[n][h*32+f] * a[h][f]
// Block = 128 threads (one per output channel), 8 nodes per batch.
// W lives in LDS (64KB); x batch transposed in LDS for broadcast float4 reads.
// ---------------------------------------------------------------------------
template<bool STORE>
__global__ __launch_bounds__(128)
void proj_kernel(const float* __restrict__ X, const float* __restrict__ W,
                 const float* __restrict__ a, float* __restrict__ proj,
                 float* __restrict__ scores, int nbatch)
{
    __shared__ float Wl[FIN * C];      // [k][c], c stride 1 -> 2-way (free) on reads
    __shared__ float xl[FIN * 8];      // [k][j]
    const int tid = threadIdx.x;       // output channel c = h*32+f

    const float4* W4  = (const float4*)W;
    float4*       Wl4 = (float4*)Wl;
    #pragma unroll
    for (int i = 0; i < (FIN * C / 4) / 128; ++i)
        Wl4[tid + i * 128] = W4[tid + i * 128];

    const float av = a[tid];           // a flat [h*32+f] == channel tid

    for (int b = blockIdx.x; b < nbatch; b += gridDim.x) {
        const int node0 = b * 8;
        __syncthreads();               // protect xl (and Wl on first iter)
        #pragma unroll
        for (int r = 0; r < 8; ++r)
            xl[tid * 8 + r] = X[(size_t)(node0 + r) * FIN + tid];
        __syncthreads();

        float acc[8];
        #pragma unroll
        for (int j = 0; j < 8; ++j) acc[j] = 0.f;

        #pragma unroll 4
        for (int k = 0; k < FIN; ++k) {
            const float  w  = Wl[k * C + tid];
            const float4 xa = *(const float4*)(xl + k * 8);
            const float4 xb = *(const float4*)(xl + k * 8 + 4);
            acc[0] = fmaf(xa.x, w, acc[0]);
            acc[1] = fmaf(xa.y, w, acc[1]);
            acc[2] = fmaf(xa.z, w, acc[2]);
            acc[3] = fmaf(xa.w, w, acc[3]);
            acc[4] = fmaf(xb.x, w, acc[4]);
            acc[5] = fmaf(xb.y, w, acc[5]);
            acc[6] = fmaf(xb.z, w, acc[6]);
            acc[7] = fmaf(xb.w, w, acc[7]);
        }

        if (STORE) {
            #pragma unroll
            for (int j = 0; j < 8; ++j)
                proj[(size_t)(node0 + j) * C + tid] = acc[j];
        }

        // fused score reduction over each 32-lane head group
        const int h   = tid >> 5;
        const int l32 = tid & 31;
        #pragma unroll
        for (int j = 0; j < 8; ++j) {
            float s = acc[j] * av;
            #pragma unroll
            for (int off = 16; off; off >>= 1)
                s += __shfl_down(s, off, 32);
            if (l32 == 0)
                scores[(node0 + j) * NHH + h] = s;
        }
    }
}

// ---------------------------------------------------------------------------
// Pass 1 over edges: global max of leaky_relu(score_src[si]+score_trg[ti])
// ---------------------------------------------------------------------------
__global__ __launch_bounds__(256)
void edge_max_kernel(const int* __restrict__ ei, const float* __restrict__ ssrc,
                     const float* __restrict__ strg, float* __restrict__ partial)
{
    float m = -1e30f;
    for (int e = blockIdx.x * 256 + threadIdx.x; e < NEDGE; e += gridDim.x * 256) {
        const int si = ei[e];
        const int ti = ei[NEDGE + e];
        const float4 a = *(const float4*)(ssrc + si * 4);
        const float4 b = *(const float4*)(strg + ti * 4);
        m = fmaxf(m, lrelu(a.x + b.x));
        m = fmaxf(m, lrelu(a.y + b.y));
        m = fmaxf(m, lrelu(a.z + b.z));
        m = fmaxf(m, lrelu(a.w + b.w));
    }
    #pragma unroll
    for (int off = 32; off; off >>= 1) m = fmaxf(m, __shfl_down(m, off, 64));
    __shared__ float wm[4];
    if ((threadIdx.x & 63) == 0) wm[threadIdx.x >> 6] = m;
    __syncthreads();
    if (threadIdx.x == 0)
        partial[blockIdx.x] = fmaxf(fmaxf(wm[0], wm[1]), fmaxf(wm[2], wm[3]));
}

__global__ __launch_bounds__(256)
void reduce_max_kernel(const float* __restrict__ partial, float* __restrict__ gmax)
{
    float m = partial[threadIdx.x];
    m = fmaxf(m, partial[threadIdx.x + 256]);
    m = fmaxf(m, partial[threadIdx.x + 512]);
    m = fmaxf(m, partial[threadIdx.x + 768]);
    #pragma unroll
    for (int off = 32; off; off >>= 1) m = fmaxf(m, __shfl_down(m, off, 64));
    __shared__ float wm[4];
    if ((threadIdx.x & 63) == 0) wm[threadIdx.x >> 6] = m;
    __syncthreads();
    if (threadIdx.x == 0)
        gmax[0] = fmaxf(fmaxf(wm[0], wm[1]), fmaxf(wm[2], wm[3]));
}

// ---------------------------------------------------------------------------
// Pass 2 over edges: exp(score - M), store per-edge, atomically accumulate
// softmax denominator per (target, head).
// ---------------------------------------------------------------------------
__global__ __launch_bounds__(256)
void edge_exp_kernel(const int* __restrict__ ei, const float* __restrict__ ssrc,
                     const float* __restrict__ strg, const float* __restrict__ gmax,
                     float* __restrict__ exps, float* __restrict__ denom)
{
    const int e = blockIdx.x * 256 + threadIdx.x;
    if (e >= NEDGE) return;
    const float M = gmax[0];
    const int si = ei[e];
    const int ti = ei[NEDGE + e];
    const float4 a = *(const float4*)(ssrc + si * 4);
    const float4 b = *(const float4*)(strg + ti * 4);
    float4 ev;
    ev.x = expf(lrelu(a.x + b.x) - M);
    ev.y = expf(lrelu(a.y + b.y) - M);
    ev.z = expf(lrelu(a.z + b.z) - M);
    ev.w = expf(lrelu(a.w + b.w) - M);
    *(float4*)(exps + (size_t)e * 4) = ev;
    __hip_atomic_fetch_add(denom + ti * 4 + 0, ev.x, __ATOMIC_RELAXED, __HIP_MEMORY_SCOPE_AGENT);
    __hip_atomic_fetch_add(denom + ti * 4 + 1, ev.y, __ATOMIC_RELAXED, __HIP_MEMORY_SCOPE_AGENT);
    __hip_atomic_fetch_add(denom + ti * 4 + 2, ev.z, __ATOMIC_RELAXED, __HIP_MEMORY_SCOPE_AGENT);
    __hip_atomic_fetch_add(denom + ti * 4 + 3, ev.w, __ATOMIC_RELAXED, __HIP_MEMORY_SCOPE_AGENT);
}

// ---------------------------------------------------------------------------
// Pass 3 over edges: out[ti, c] += src_proj[si, c] * att[e, h(c)]
// 32 lanes per edge, float4 per lane -> one 512B coalesced segment per edge.
// ---------------------------------------------------------------------------
__global__ __launch_bounds__(256)
void aggregate_kernel(const int* __restrict__ ei, const float* __restrict__ src_proj,
                      const float* __restrict__ exps, const float* __restrict__ denom,
                      float* __restrict__ out)
{
    const int t = blockIdx.x * 256 + threadIdx.x;
    const int e = t >> 5;
    if (e >= NEDGE) return;
    const int lane = threadIdx.x & 31;   // feature group: channels lane*4..lane*4+3
    const int si = ei[e];
    const int ti = ei[NEDGE + e];
    const int h = lane >> 3;
    const float att = exps[(size_t)e * 4 + h] / (denom[ti * 4 + h] + 1e-16f);
    const float4 v = *(const float4*)(src_proj + (size_t)si * C + lane * 4);
    float* o = out + (size_t)ti * C + lane * 4;
    __hip_atomic_fetch_add(o + 0, v.x * att, __ATOMIC_RELAXED, __HIP_MEMORY_SCOPE_AGENT);
    __hip_atomic_fetch_add(o + 1, v.y * att, __ATOMIC_RELAXED, __HIP_MEMORY_SCOPE_AGENT);
    __hip_atomic_fetch_add(o + 2, v.z * att, __ATOMIC_RELAXED, __HIP_MEMORY_SCOPE_AGENT);
    __hip_atomic_fetch_add(o + 3, v.w * att, __ATOMIC_RELAXED, __HIP_MEMORY_SCOPE_AGENT);
}

// ---------------------------------------------------------------------------
extern "C" void kernel_launch(void* const* d_in, const int* in_sizes, int n_in,
                              void* d_out, int out_size, void* d_ws, size_t ws_size,
                              hipStream_t stream)
{
    const float* trg   = (const float*)d_in[0];
    const float* src   = (const float*)d_in[1];
    const int*   ei    = (const int*)d_in[2];
    const float* Wt    = (const float*)d_in[3];
    const float* Ws    = (const float*)d_in[4];
    const float* a_src = (const float*)d_in[5];
    const float* a_trg = (const float*)d_in[6];
    float* out = (float*)d_out;

    // workspace layout (floats), all 16B aligned
    float* ws       = (float*)d_ws;
    float* src_proj = ws;                                  // 6,400,000
    float* ssrc     = src_proj + (size_t)NNODE * C;        //   200,000
    float* strg     = ssrc + NNODE * NHH;                  //   200,000
    float* exps     = strg + NNODE * NHH;                  // 3,200,000
    float* denom    = exps + (size_t)NEDGE * NHH;          //   200,000
    float* partial  = denom + NNODE * NHH;                 //     1,024
    float* gmax     = partial + 1024;                      //         1

    hipMemsetAsync(d_out, 0, (size_t)NNODE * C * sizeof(float), stream);
    hipMemsetAsync(denom, 0, (size_t)NNODE * NHH * sizeof(float), stream);

    const int nbatch = NNODE / 8;  // 6250 exact
    proj_kernel<false><<<1024, 128, 0, stream>>>(trg, Wt, a_trg, nullptr, strg, nbatch);
    proj_kernel<true ><<<1024, 128, 0, stream>>>(src, Ws, a_src, src_proj, ssrc, nbatch);
    edge_max_kernel<<<1024, 256, 0, stream>>>(ei, ssrc, strg, partial);
    reduce_max_kernel<<<1, 256, 0, stream>>>(partial, gmax);
    edge_exp_kernel<<<(NEDGE + 255) / 256, 256, 0, stream>>>(ei, ssrc, strg, gmax, exps, denom);
    aggregate_kernel<<<(NEDGE * 32) / 256, 256, 0, stream>>>(ei, src_proj, exps, denom, out);
}

// Round 2
// 433.679 us; speedup vs baseline: 4.1061x; 4.1061x over previous
//
#include <hip/hip_runtime.h>
#include <math.h>

#define FIN   128
#define C     128      // NH*FOUT
#define NHH   4
#define NNODE 50000
#define NEDGE 800000
#define NB_SCAN 196    // ceil(50000/256)

__device__ __forceinline__ float lrelu(float x) { return x > 0.f ? x : 0.2f * x; }

// ---------------------------------------------------------------------------
// Projection + fused per-node score: proj = X @ W  (N x 128 @ 128 x 128)
// scores[n][h] = sum_f proj[n][h*32+f] * a[h][f]
// ---------------------------------------------------------------------------
template<bool STORE>
__global__ __launch_bounds__(128)
void proj_kernel(const float* __restrict__ X, const float* __restrict__ W,
                 const float* __restrict__ a, float* __restrict__ proj,
                 float* __restrict__ scores, int nbatch)
{
    __shared__ float Wl[FIN * C];
    __shared__ float xl[FIN * 8];
    const int tid = threadIdx.x;

    const float4* W4  = (const float4*)W;
    float4*       Wl4 = (float4*)Wl;
    #pragma unroll
    for (int i = 0; i < (FIN * C / 4) / 128; ++i)
        Wl4[tid + i * 128] = W4[tid + i * 128];

    const float av = a[tid];

    for (int b = blockIdx.x; b < nbatch; b += gridDim.x) {
        const int node0 = b * 8;
        __syncthreads();
        #pragma unroll
        for (int r = 0; r < 8; ++r)
            xl[tid * 8 + r] = X[(size_t)(node0 + r) * FIN + tid];
        __syncthreads();

        float acc[8];
        #pragma unroll
        for (int j = 0; j < 8; ++j) acc[j] = 0.f;

        #pragma unroll 4
        for (int k = 0; k < FIN; ++k) {
            const float  w  = Wl[k * C + tid];
            const float4 xa = *(const float4*)(xl + k * 8);
            const float4 xb = *(const float4*)(xl + k * 8 + 4);
            acc[0] = fmaf(xa.x, w, acc[0]);
            acc[1] = fmaf(xa.y, w, acc[1]);
            acc[2] = fmaf(xa.z, w, acc[2]);
            acc[3] = fmaf(xa.w, w, acc[3]);
            acc[4] = fmaf(xb.x, w, acc[4]);
            acc[5] = fmaf(xb.y, w, acc[5]);
            acc[6] = fmaf(xb.z, w, acc[6]);
            acc[7] = fmaf(xb.w, w, acc[7]);
        }

        if (STORE) {
            #pragma unroll
            for (int j = 0; j < 8; ++j)
                proj[(size_t)(node0 + j) * C + tid] = acc[j];
        }

        const int h   = tid >> 5;
        const int l32 = tid & 31;
        #pragma unroll
        for (int j = 0; j < 8; ++j) {
            float s = acc[j] * av;
            #pragma unroll
            for (int off = 16; off; off >>= 1)
                s += __shfl_down(s, off, 32);
            if (l32 == 0)
                scores[(node0 + j) * NHH + h] = s;
        }
    }
}

// ---------------------------------------------------------------------------
// Edge pass 1: global max of scores AND degree histogram of targets.
// ---------------------------------------------------------------------------
__global__ __launch_bounds__(256)
void edge_max_count_kernel(const int* __restrict__ ei, const float* __restrict__ ssrc,
                           const float* __restrict__ strg, float* __restrict__ partial,
                           int* __restrict__ counts)
{
    float m = -1e30f;
    for (int e = blockIdx.x * 256 + threadIdx.x; e < NEDGE; e += gridDim.x * 256) {
        const int si = ei[e];
        const int ti = ei[NEDGE + e];
        atomicAdd(counts + ti, 1);
        const float4 a = *(const float4*)(ssrc + si * 4);
        const float4 b = *(const float4*)(strg + ti * 4);
        m = fmaxf(m, lrelu(a.x + b.x));
        m = fmaxf(m, lrelu(a.y + b.y));
        m = fmaxf(m, lrelu(a.z + b.z));
        m = fmaxf(m, lrelu(a.w + b.w));
    }
    #pragma unroll
    for (int off = 32; off; off >>= 1) m = fmaxf(m, __shfl_down(m, off, 64));
    __shared__ float wm[4];
    if ((threadIdx.x & 63) == 0) wm[threadIdx.x >> 6] = m;
    __syncthreads();
    if (threadIdx.x == 0)
        partial[blockIdx.x] = fmaxf(fmaxf(wm[0], wm[1]), fmaxf(wm[2], wm[3]));
}

__global__ __launch_bounds__(256)
void reduce_max_kernel(const float* __restrict__ partial, float* __restrict__ gmax)
{
    float m = partial[threadIdx.x];
    m = fmaxf(m, partial[threadIdx.x + 256]);
    m = fmaxf(m, partial[threadIdx.x + 512]);
    m = fmaxf(m, partial[threadIdx.x + 768]);
    #pragma unroll
    for (int off = 32; off; off >>= 1) m = fmaxf(m, __shfl_down(m, off, 64));
    __shared__ float wm[4];
    if ((threadIdx.x & 63) == 0) wm[threadIdx.x >> 6] = m;
    __syncthreads();
    if (threadIdx.x == 0)
        gmax[0] = fmaxf(fmaxf(wm[0], wm[1]), fmaxf(wm[2], wm[3]));
}

// ---------------------------------------------------------------------------
// 3-kernel exclusive scan over counts[NNODE] -> offsets[NNODE]
// ---------------------------------------------------------------------------
__global__ __launch_bounds__(256)
void scan_a_kernel(const int* __restrict__ counts, int* __restrict__ offsets,
                   int* __restrict__ bsum)
{
    __shared__ int s[256];
    const int tid = threadIdx.x;
    const int i = blockIdx.x * 256 + tid;
    const int v = (i < NNODE) ? counts[i] : 0;
    s[tid] = v;
    __syncthreads();
    #pragma unroll
    for (int off = 1; off < 256; off <<= 1) {
        const int x = (tid >= off) ? s[tid - off] : 0;
        __syncthreads();
        s[tid] += x;
        __syncthreads();
    }
    if (i < NNODE) offsets[i] = s[tid] - v;   // exclusive
    if (tid == 255) bsum[blockIdx.x] = s[tid];
}

__global__ __launch_bounds__(256)
void scan_b_kernel(int* __restrict__ bsum, int* __restrict__ bofs)
{
    __shared__ int s[256];
    const int tid = threadIdx.x;
    const int v = (tid < NB_SCAN) ? bsum[tid] : 0;
    s[tid] = v;
    __syncthreads();
    #pragma unroll
    for (int off = 1; off < 256; off <<= 1) {
        const int x = (tid >= off) ? s[tid - off] : 0;
        __syncthreads();
        s[tid] += x;
        __syncthreads();
    }
    if (tid < NB_SCAN) bofs[tid] = s[tid] - v;   // exclusive
}

__global__ __launch_bounds__(256)
void scan_c_kernel(int* __restrict__ offsets, const int* __restrict__ bofs)
{
    const int i = blockIdx.x * 256 + threadIdx.x;
    if (i < NNODE) offsets[i] += bofs[blockIdx.x];
}

// ---------------------------------------------------------------------------
// Edge pass 2: exp(lrelu(score)-M), scatter into CSR slots by target.
// ---------------------------------------------------------------------------
__global__ __launch_bounds__(256)
void exp_scatter_kernel(const int* __restrict__ ei, const float* __restrict__ ssrc,
                        const float* __restrict__ strg, const float* __restrict__ gmax,
                        int* __restrict__ cursor, int* __restrict__ sorted_si,
                        float* __restrict__ sorted_exp)
{
    const int e = blockIdx.x * 256 + threadIdx.x;
    if (e >= NEDGE) return;
    const float M = gmax[0];
    const int si = ei[e];
    const int ti = ei[NEDGE + e];
    const float4 a = *(const float4*)(ssrc + si * 4);
    const float4 b = *(const float4*)(strg + ti * 4);
    float4 ev;
    ev.x = expf(lrelu(a.x + b.x) - M);
    ev.y = expf(lrelu(a.y + b.y) - M);
    ev.z = expf(lrelu(a.z + b.z) - M);
    ev.w = expf(lrelu(a.w + b.w) - M);
    const int p = atomicAdd(cursor + ti, 1);
    sorted_si[p] = si;
    *(float4*)(sorted_exp + (size_t)p * 4) = ev;
}

// ---------------------------------------------------------------------------
// Aggregate (gather): one 64-lane wave per target, lane owns 2 channels.
// out[t,c] = (sum_j e_j * v_j[c]) / (sum_j e_j + 1e-16)
// ---------------------------------------------------------------------------
__global__ __launch_bounds__(256)
void aggregate_gather_kernel(const int* __restrict__ offsets, const int* __restrict__ counts,
                             const int* __restrict__ sorted_si,
                             const float* __restrict__ sorted_exp,
                             const float* __restrict__ src_proj,
                             float* __restrict__ out)
{
    const int lane = threadIdx.x & 63;
    const int wave = threadIdx.x >> 6;
    const int h = lane >> 4;              // channel 2*lane -> head (2*lane)>>5
    const int t = blockIdx.x * 4 + wave;
    if (t >= NNODE) return;

    const int start = offsets[t];
    const int end   = start + counts[t];
    float d = 0.f;
    float2 acc = make_float2(0.f, 0.f);
    for (int j = start; j < end; ++j) {
        const int   si = sorted_si[j];
        const float ev = sorted_exp[(size_t)j * 4 + h];
        const float2 v = *(const float2*)(src_proj + (size_t)si * C + lane * 2);
        acc.x = fmaf(v.x, ev, acc.x);
        acc.y = fmaf(v.y, ev, acc.y);
        d += ev;
    }
    const float inv = 1.0f / (d + 1e-16f);
    acc.x *= inv;
    acc.y *= inv;
    *(float2*)(out + (size_t)t * C + lane * 2) = acc;
}

// ---------------------------------------------------------------------------
extern "C" void kernel_launch(void* const* d_in, const int* in_sizes, int n_in,
                              void* d_out, int out_size, void* d_ws, size_t ws_size,
                              hipStream_t stream)
{
    const float* trg   = (const float*)d_in[0];
    const float* src   = (const float*)d_in[1];
    const int*   ei    = (const int*)d_in[2];
    const float* Wt    = (const float*)d_in[3];
    const float* Ws    = (const float*)d_in[4];
    const float* a_src = (const float*)d_in[5];
    const float* a_trg = (const float*)d_in[6];
    float* out = (float*)d_out;

    // workspace layout
    float* ws         = (float*)d_ws;
    float* src_proj   = ws;                                    // 6,400,000 f
    float* ssrc       = src_proj + (size_t)NNODE * C;          //   200,000 f
    float* strg       = ssrc + NNODE * NHH;                    //   200,000 f
    float* sorted_exp = strg + NNODE * NHH;                    // 3,200,000 f
    float* partial    = sorted_exp + (size_t)NEDGE * NHH;      //     1,024 f
    float* gmax       = partial + 1024;                        //         4 f
    int*   counts     = (int*)(gmax + 4);                      //    50,000 i
    int*   offsets    = counts + NNODE;                        //    50,000 i
    int*   cursor     = offsets + NNODE;                       //    50,000 i
    int*   bsum       = cursor + NNODE;                        //       256 i
    int*   bofs       = bsum + 256;                            //       256 i
    int*   sorted_si  = bofs + 256;                            //   800,000 i

    hipMemsetAsync(counts, 0, NNODE * sizeof(int), stream);

    const int nbatch = NNODE / 8;  // 6250 exact
    proj_kernel<false><<<1024, 128, 0, stream>>>(trg, Wt, a_trg, nullptr, strg, nbatch);
    proj_kernel<true ><<<1024, 128, 0, stream>>>(src, Ws, a_src, src_proj, ssrc, nbatch);
    edge_max_count_kernel<<<1024, 256, 0, stream>>>(ei, ssrc, strg, partial, counts);
    reduce_max_kernel<<<1, 256, 0, stream>>>(partial, gmax);
    scan_a_kernel<<<NB_SCAN, 256, 0, stream>>>(counts, offsets, bsum);
    scan_b_kernel<<<1, 256, 0, stream>>>(bsum, bofs);
    scan_c_kernel<<<NB_SCAN, 256, 0, stream>>>(offsets, bofs);
    hipMemcpyAsync(cursor, offsets, NNODE * sizeof(int), hipMemcpyDeviceToDevice, stream);
    exp_scatter_kernel<<<(NEDGE + 255) / 256, 256, 0, stream>>>(ei, ssrc, strg, gmax,
                                                                cursor, sorted_si, sorted_exp);
    aggregate_gather_kernel<<<(NNODE + 3) / 4, 256, 0, stream>>>(offsets, counts, sorted_si,
                                                                 sorted_exp, src_proj, out);
}

// Round 3
// 303.823 us; speedup vs baseline: 5.8611x; 1.4274x over previous
//
#include <hip/hip_runtime.h>
#include <math.h>

#define FIN   128
#define C     128      // NH*FOUT
#define NHH   4
#define NNODE 50000
#define NEDGE 800000
#define NB_SCAN 196    // ceil(50000/256)
#define NTILE 782      // ceil(50000/64)
#define XPAD  66       // 64 nodes + 2 pad: reads (2k+lane)%32 and writes both 2-way (free)

__device__ __forceinline__ float lrelu(float x) { return x > 0.f ? x : 0.2f * x; }

// ---------------------------------------------------------------------------
// Projection + fused per-node score, v2.
// One block = 64 nodes; wave w computes channels [32w, 32w+32) == head w.
// lane = node. X^T tile in LDS (33KB); W read via wave-uniform scalar loads
// (SMEM pipe) -> k-loop is 32 FMA per 1 ds_read_b32: VALU-bound.
// ---------------------------------------------------------------------------
template<bool STORE>
__global__ __launch_bounds__(256)
void proj2_kernel(const float* __restrict__ X, const float* __restrict__ W,
                  const float* __restrict__ a, float* __restrict__ proj,
                  float* __restrict__ scores)
{
    __shared__ float xl[FIN * XPAD];
    const int tid   = threadIdx.x;
    const int lane  = tid & 63;
    const int wave  = __builtin_amdgcn_readfirstlane(tid >> 6);
    const int cbase = wave << 5;           // head offset, 32 channels
    const int n0    = blockIdx.x * 64;

    // stage X^T: 64 rows x 128 k. Thread t loads float4 (row=t>>2, c4=(t&3)+4i).
    {
        const int row = tid >> 2;
        const int c4b = tid & 3;
        const float4* X4 = (const float4*)X;
        #pragma unroll
        for (int i = 0; i < 8; ++i) {
            const int c4 = c4b + (i << 2);           // 0..31
            float4 v = make_float4(0.f, 0.f, 0.f, 0.f);
            if (n0 + row < NNODE) v = X4[(size_t)(n0 + row) * 32 + c4];
            const int k0 = c4 << 2;
            xl[(k0 + 0) * XPAD + row] = v.x;
            xl[(k0 + 1) * XPAD + row] = v.y;
            xl[(k0 + 2) * XPAD + row] = v.z;
            xl[(k0 + 3) * XPAD + row] = v.w;
        }
    }
    __syncthreads();

    float acc[32];
    #pragma unroll
    for (int j = 0; j < 32; ++j) acc[j] = 0.f;

    #pragma unroll 2
    for (int k = 0; k < FIN; ++k) {
        const float xv = xl[k * XPAD + lane];
        const float4* wr = (const float4*)(W + (k << 7) + cbase);  // wave-uniform
        #pragma unroll
        for (int q = 0; q < 8; ++q) {
            const float4 wv = wr[q];
            acc[4*q+0] = fmaf(xv, wv.x, acc[4*q+0]);
            acc[4*q+1] = fmaf(xv, wv.y, acc[4*q+1]);
            acc[4*q+2] = fmaf(xv, wv.z, acc[4*q+2]);
            acc[4*q+3] = fmaf(xv, wv.w, acc[4*q+3]);
        }
    }

    const int n = n0 + lane;
    if (n < NNODE) {
        if (STORE) {
            float4* P4 = (float4*)(proj + (size_t)n * C + cbase);
            #pragma unroll
            for (int q = 0; q < 8; ++q)
                P4[q] = make_float4(acc[4*q], acc[4*q+1], acc[4*q+2], acc[4*q+3]);
        }
        float s = 0.f;
        #pragma unroll
        for (int j = 0; j < 32; ++j) s = fmaf(acc[j], a[cbase + j], s);
        scores[n * NHH + wave] = s;
    }
}

// ---------------------------------------------------------------------------
// Edge pass 1: degree histogram of targets (reads only ti stream).
// ---------------------------------------------------------------------------
__global__ __launch_bounds__(256)
void count_kernel(const int* __restrict__ ei, int* __restrict__ counts)
{
    const int e = blockIdx.x * 256 + threadIdx.x;
    if (e >= NEDGE) return;
    atomicAdd(counts + ei[NEDGE + e], 1);
}

// ---------------------------------------------------------------------------
// 3-kernel exclusive scan over counts[NNODE] -> offsets[NNODE] (+cursor copy)
// ---------------------------------------------------------------------------
__global__ __launch_bounds__(256)
void scan_a_kernel(const int* __restrict__ counts, int* __restrict__ offsets,
                   int* __restrict__ bsum)
{
    __shared__ int s[256];
    const int tid = threadIdx.x;
    const int i = blockIdx.x * 256 + tid;
    const int v = (i < NNODE) ? counts[i] : 0;
    s[tid] = v;
    __syncthreads();
    #pragma unroll
    for (int off = 1; off < 256; off <<= 1) {
        const int x = (tid >= off) ? s[tid - off] : 0;
        __syncthreads();
        s[tid] += x;
        __syncthreads();
    }
    if (i < NNODE) offsets[i] = s[tid] - v;
    if (tid == 255) bsum[blockIdx.x] = s[tid];
}

__global__ __launch_bounds__(256)
void scan_b_kernel(int* __restrict__ bsum, int* __restrict__ bofs)
{
    __shared__ int s[256];
    const int tid = threadIdx.x;
    const int v = (tid < NB_SCAN) ? bsum[tid] : 0;
    s[tid] = v;
    __syncthreads();
    #pragma unroll
    for (int off = 1; off < 256; off <<= 1) {
        const int x = (tid >= off) ? s[tid - off] : 0;
        __syncthreads();
        s[tid] += x;
        __syncthreads();
    }
    if (tid < NB_SCAN) bofs[tid] = s[tid] - v;
}

__global__ __launch_bounds__(256)
void scan_c_kernel(int* __restrict__ offsets, const int* __restrict__ bofs,
                   int* __restrict__ cursor)
{
    const int i = blockIdx.x * 256 + threadIdx.x;
    if (i < NNODE) {
        const int v = offsets[i] + bofs[blockIdx.x];
        offsets[i] = v;
        cursor[i]  = v;
    }
}

// ---------------------------------------------------------------------------
// Edge pass 2: scatter source ids into CSR slots by target (permutation only).
// ---------------------------------------------------------------------------
__global__ __launch_bounds__(256)
void scatter_kernel(const int* __restrict__ ei, int* __restrict__ cursor,
                    int* __restrict__ sorted_si)
{
    const int e = blockIdx.x * 256 + threadIdx.x;
    if (e >= NEDGE) return;
    const int si = ei[e];
    const int ti = ei[NEDGE + e];
    const int p = atomicAdd(cursor + ti, 1);
    sorted_si[p] = si;
}

// ---------------------------------------------------------------------------
// Aggregate (gather): one 64-lane wave per target, lane owns 2 channels.
// exp recomputed in-loop from scores (no global max: cancels in the ratio).
// out[t,c] = (sum_j e_j * v_j[c]) / (sum_j e_j + 1e-16)
// ---------------------------------------------------------------------------
__global__ __launch_bounds__(256)
void aggregate_gather_kernel(const int* __restrict__ offsets, const int* __restrict__ counts,
                             const int* __restrict__ sorted_si,
                             const float* __restrict__ ssrc, const float* __restrict__ strg,
                             const float* __restrict__ src_proj,
                             float* __restrict__ out)
{
    const int lane = threadIdx.x & 63;
    const int wv   = threadIdx.x >> 6;
    const int t = blockIdx.x * 4 + wv;
    if (t >= NNODE) return;
    const int h = lane >> 4;               // channels 2*lane,2*lane+1 -> head
    const float st = strg[t * NHH + h];
    const int start = offsets[t];
    const int end   = start + counts[t];
    const float2* SP2 = (const float2*)src_proj;

    float2 acc = make_float2(0.f, 0.f);
    float d = 0.f;
    int j = start;
    for (; j + 4 <= end; j += 4) {
        const int si0 = sorted_si[j + 0];
        const int si1 = sorted_si[j + 1];
        const int si2 = sorted_si[j + 2];
        const int si3 = sorted_si[j + 3];
        const float s0 = ssrc[si0 * NHH + h];
        const float s1 = ssrc[si1 * NHH + h];
        const float s2 = ssrc[si2 * NHH + h];
        const float s3 = ssrc[si3 * NHH + h];
        const float2 v0 = SP2[(size_t)si0 * 64 + lane];
        const float2 v1 = SP2[(size_t)si1 * 64 + lane];
        const float2 v2 = SP2[(size_t)si2 * 64 + lane];
        const float2 v3 = SP2[(size_t)si3 * 64 + lane];
        const float e0 = __expf(lrelu(s0 + st));
        const float e1 = __expf(lrelu(s1 + st));
        const float e2 = __expf(lrelu(s2 + st));
        const float e3 = __expf(lrelu(s3 + st));
        acc.x = fmaf(v0.x, e0, acc.x); acc.y = fmaf(v0.y, e0, acc.y);
        acc.x = fmaf(v1.x, e1, acc.x); acc.y = fmaf(v1.y, e1, acc.y);
        acc.x = fmaf(v2.x, e2, acc.x); acc.y = fmaf(v2.y, e2, acc.y);
        acc.x = fmaf(v3.x, e3, acc.x); acc.y = fmaf(v3.y, e3, acc.y);
        d += e0 + e1 + e2 + e3;
    }
    for (; j < end; ++j) {
        const int si = sorted_si[j];
        const float e = __expf(lrelu(ssrc[si * NHH + h] + st));
        const float2 v = SP2[(size_t)si * 64 + lane];
        acc.x = fmaf(v.x, e, acc.x);
        acc.y = fmaf(v.y, e, acc.y);
        d += e;
    }
    const float inv = 1.0f / (d + 1e-16f);
    ((float2*)out)[(size_t)t * 64 + lane] = make_float2(acc.x * inv, acc.y * inv);
}

// ---------------------------------------------------------------------------
extern "C" void kernel_launch(void* const* d_in, const int* in_sizes, int n_in,
                              void* d_out, int out_size, void* d_ws, size_t ws_size,
                              hipStream_t stream)
{
    const float* trg   = (const float*)d_in[0];
    const float* src   = (const float*)d_in[1];
    const int*   ei    = (const int*)d_in[2];
    const float* Wt    = (const float*)d_in[3];
    const float* Ws    = (const float*)d_in[4];
    const float* a_src = (const float*)d_in[5];
    const float* a_trg = (const float*)d_in[6];
    float* out = (float*)d_out;

    // workspace layout
    float* ws         = (float*)d_ws;
    float* src_proj   = ws;                                    // 6,400,000 f
    float* ssrc       = src_proj + (size_t)NNODE * C;          //   200,000 f
    float* strg       = ssrc + NNODE * NHH;                    //   200,000 f
    int*   counts     = (int*)(strg + NNODE * NHH);            //    50,000 i
    int*   offsets    = counts + NNODE;                        //    50,000 i
    int*   cursor     = offsets + NNODE;                       //    50,000 i
    int*   bsum       = cursor + NNODE;                        //       256 i
    int*   bofs       = bsum + 256;                            //       256 i
    int*   sorted_si  = bofs + 256;                            //   800,000 i

    hipMemsetAsync(counts, 0, NNODE * sizeof(int), stream);

    proj2_kernel<false><<<NTILE, 256, 0, stream>>>(trg, Wt, a_trg, nullptr, strg);
    proj2_kernel<true ><<<NTILE, 256, 0, stream>>>(src, Ws, a_src, src_proj, ssrc);
    count_kernel<<<(NEDGE + 255) / 256, 256, 0, stream>>>(ei, counts);
    scan_a_kernel<<<NB_SCAN, 256, 0, stream>>>(counts, offsets, bsum);
    scan_b_kernel<<<1, 256, 0, stream>>>(bsum, bofs);
    scan_c_kernel<<<NB_SCAN, 256, 0, stream>>>(offsets, bofs, cursor);
    scatter_kernel<<<(NEDGE + 255) / 256, 256, 0, stream>>>(ei, cursor, sorted_si);
    aggregate_gather_kernel<<<(NNODE + 3) / 4, 256, 0, stream>>>(offsets, counts, sorted_si,
                                                                 ssrc, strg, src_proj, out);
}

// Round 4
// 288.778 us; speedup vs baseline: 6.1665x; 1.0521x over previous
//
#include <hip/hip_runtime.h>
#include <math.h>

#define FIN   128
#define C     128      // NH*FOUT
#define NHH   4
#define NNODE 50000
#define NEDGE 800000
#define NB_SCAN 196    // ceil(50000/256)
#define NTILE 782      // ceil(50000/64)
#define XPAD  66       // 64 nodes + 2 pad

__device__ __forceinline__ float lrelu(float x) { return x > 0.f ? x : 0.2f * x; }

__device__ __forceinline__ unsigned int bf16rne(float x) {
    unsigned int u = __float_as_uint(x);
    return (u + 0x7fffu + ((u >> 16) & 1u)) >> 16;   // rounded upper 16 bits
}

// ---------------------------------------------------------------------------
// Projection + fused per-node score + fused edge-pass tail.
// One block = 64 nodes; wave w computes channels [32w,32w+32) == head w.
// MODE 0 (trg): scores only; tail = target-degree histogram.
// MODE 1 (src): store proj as packed bf16x2; tail = CSR scatter of source ids.
// ---------------------------------------------------------------------------
template<int MODE>
__global__ __launch_bounds__(256)
void proj2_kernel(const float* __restrict__ X, const float* __restrict__ W,
                  const float* __restrict__ a, unsigned int* __restrict__ proj_bf,
                  float* __restrict__ scores, const int* __restrict__ ei,
                  int* __restrict__ cnt_or_cur, int* __restrict__ sorted_si)
{
    __shared__ float xl[FIN * XPAD];
    const int tid   = threadIdx.x;
    const int lane  = tid & 63;
    const int wave  = __builtin_amdgcn_readfirstlane(tid >> 6);
    const int cbase = wave << 5;
    const int n0    = blockIdx.x * 64;

    // stage X^T tile
    {
        const int row = tid >> 2;
        const int c4b = tid & 3;
        const float4* X4 = (const float4*)X;
        #pragma unroll
        for (int i = 0; i < 8; ++i) {
            const int c4 = c4b + (i << 2);
            float4 v = make_float4(0.f, 0.f, 0.f, 0.f);
            if (n0 + row < NNODE) v = X4[(size_t)(n0 + row) * 32 + c4];
            const int k0 = c4 << 2;
            xl[(k0 + 0) * XPAD + row] = v.x;
            xl[(k0 + 1) * XPAD + row] = v.y;
            xl[(k0 + 2) * XPAD + row] = v.z;
            xl[(k0 + 3) * XPAD + row] = v.w;
        }
    }
    __syncthreads();

    float acc[32];
    #pragma unroll
    for (int j = 0; j < 32; ++j) acc[j] = 0.f;

    #pragma unroll 2
    for (int k = 0; k < FIN; ++k) {
        const float xv = xl[k * XPAD + lane];
        const float4* wr = (const float4*)(W + (k << 7) + cbase);  // wave-uniform
        #pragma unroll
        for (int q = 0; q < 8; ++q) {
            const float4 wv = wr[q];
            acc[4*q+0] = fmaf(xv, wv.x, acc[4*q+0]);
            acc[4*q+1] = fmaf(xv, wv.y, acc[4*q+1]);
            acc[4*q+2] = fmaf(xv, wv.z, acc[4*q+2]);
            acc[4*q+3] = fmaf(xv, wv.w, acc[4*q+3]);
        }
    }

    const int n = n0 + lane;
    if (n < NNODE) {
        if (MODE == 1) {
            unsigned int pk[16];
            #pragma unroll
            for (int q = 0; q < 16; ++q) {
                const unsigned int lo = bf16rne(acc[2*q]);
                const unsigned int hiu = __float_as_uint(acc[2*q+1]);
                const unsigned int hi = (hiu + 0x7fffu + ((hiu >> 16) & 1u)) & 0xffff0000u;
                pk[q] = lo | hi;
            }
            uint4* P = (uint4*)(proj_bf + (size_t)n * 64 + (cbase >> 1));
            #pragma unroll
            for (int q = 0; q < 4; ++q)
                P[q] = make_uint4(pk[4*q], pk[4*q+1], pk[4*q+2], pk[4*q+3]);
        }
        float s = 0.f;
        #pragma unroll
        for (int j = 0; j < 32; ++j) s = fmaf(acc[j], a[cbase + j], s);
        scores[n * NHH + wave] = s;
    }

    // fused edge-pass tail (grid-stride over edges)
    const int g = blockIdx.x * 256 + tid;
    if (MODE == 0) {
        for (int e = g; e < NEDGE; e += NTILE * 256)
            atomicAdd(cnt_or_cur + ei[NEDGE + e], 1);
    } else {
        for (int e = g; e < NEDGE; e += NTILE * 256) {
            const int si = ei[e];
            const int ti = ei[NEDGE + e];
            const int p = atomicAdd(cnt_or_cur + ti, 1);
            sorted_si[p] = si;
        }
    }
}

// ---------------------------------------------------------------------------
// 3-kernel exclusive scan over counts[NNODE] -> offsets[NNODE] (+cursor copy)
// ---------------------------------------------------------------------------
__global__ __launch_bounds__(256)
void scan_a_kernel(const int* __restrict__ counts, int* __restrict__ offsets,
                   int* __restrict__ bsum)
{
    __shared__ int s[256];
    const int tid = threadIdx.x;
    const int i = blockIdx.x * 256 + tid;
    const int v = (i < NNODE) ? counts[i] : 0;
    s[tid] = v;
    __syncthreads();
    #pragma unroll
    for (int off = 1; off < 256; off <<= 1) {
        const int x = (tid >= off) ? s[tid - off] : 0;
        __syncthreads();
        s[tid] += x;
        __syncthreads();
    }
    if (i < NNODE) offsets[i] = s[tid] - v;
    if (tid == 255) bsum[blockIdx.x] = s[tid];
}

__global__ __launch_bounds__(256)
void scan_b_kernel(int* __restrict__ bsum, int* __restrict__ bofs)
{
    __shared__ int s[256];
    const int tid = threadIdx.x;
    const int v = (tid < NB_SCAN) ? bsum[tid] : 0;
    s[tid] = v;
    __syncthreads();
    #pragma unroll
    for (int off = 1; off < 256; off <<= 1) {
        const int x = (tid >= off) ? s[tid - off] : 0;
        __syncthreads();
        s[tid] += x;
        __syncthreads();
    }
    if (tid < NB_SCAN) bofs[tid] = s[tid] - v;
}

__global__ __launch_bounds__(256)
void scan_c_kernel(int* __restrict__ offsets, const int* __restrict__ bofs,
                   int* __restrict__ cursor)
{
    const int i = blockIdx.x * 256 + threadIdx.x;
    if (i < NNODE) {
        const int v = offsets[i] + bofs[blockIdx.x];
        offsets[i] = v;
        cursor[i]  = v;
    }
}

// ---------------------------------------------------------------------------
// Aggregate (gather): one 64-lane wave per target; lane owns 2 channels,
// packed as one bf16x2 dword -> 256B coalesced row per edge.
// ---------------------------------------------------------------------------
__global__ __launch_bounds__(256)
void aggregate_gather_kernel(const int* __restrict__ offsets, const int* __restrict__ counts,
                             const int* __restrict__ sorted_si,
                             const float* __restrict__ ssrc, const float* __restrict__ strg,
                             const unsigned int* __restrict__ src_proj,
                             float* __restrict__ out)
{
    const int lane = threadIdx.x & 63;
    const int wv   = threadIdx.x >> 6;
    const int t = blockIdx.x * 4 + wv;
    if (t >= NNODE) return;
    const int h = lane >> 4;
    const float st = strg[t * NHH + h];
    const int start = offsets[t];
    const int end   = start + counts[t];

    float2 acc = make_float2(0.f, 0.f);
    float d = 0.f;
    int j = start;
    for (; j + 4 <= end; j += 4) {
        const int si0 = sorted_si[j + 0];
        const int si1 = sorted_si[j + 1];
        const int si2 = sorted_si[j + 2];
        const int si3 = sorted_si[j + 3];
        const float s0 = ssrc[si0 * NHH + h];
        const float s1 = ssrc[si1 * NHH + h];
        const float s2 = ssrc[si2 * NHH + h];
        const float s3 = ssrc[si3 * NHH + h];
        const unsigned int w0 = src_proj[(size_t)si0 * 64 + lane];
        const unsigned int w1 = src_proj[(size_t)si1 * 64 + lane];
        const unsigned int w2 = src_proj[(size_t)si2 * 64 + lane];
        const unsigned int w3 = src_proj[(size_t)si3 * 64 + lane];
        const float e0 = __expf(lrelu(s0 + st));
        const float e1 = __expf(lrelu(s1 + st));
        const float e2 = __expf(lrelu(s2 + st));
        const float e3 = __expf(lrelu(s3 + st));
        acc.x = fmaf(__uint_as_float(w0 << 16),        e0, acc.x);
        acc.y = fmaf(__uint_as_float(w0 & 0xffff0000u), e0, acc.y);
        acc.x = fmaf(__uint_as_float(w1 << 16),        e1, acc.x);
        acc.y = fmaf(__uint_as_float(w1 & 0xffff0000u), e1, acc.y);
        acc.x = fmaf(__uint_as_float(w2 << 16),        e2, acc.x);
        acc.y = fmaf(__uint_as_float(w2 & 0xffff0000u), e2, acc.y);
        acc.x = fmaf(__uint_as_float(w3 << 16),        e3, acc.x);
        acc.y = fmaf(__uint_as_float(w3 & 0xffff0000u), e3, acc.y);
        d += e0 + e1 + e2 + e3;
    }
    for (; j < end; ++j) {
        const int si = sorted_si[j];
        const float e = __expf(lrelu(ssrc[si * NHH + h] + st));
        const unsigned int w = src_proj[(size_t)si * 64 + lane];
        acc.x = fmaf(__uint_as_float(w << 16),         e, acc.x);
        acc.y = fmaf(__uint_as_float(w & 0xffff0000u), e, acc.y);
        d += e;
    }
    const float inv = 1.0f / (d + 1e-16f);
    ((float2*)out)[(size_t)t * 64 + lane] = make_float2(acc.x * inv, acc.y * inv);
}

// ---------------------------------------------------------------------------
extern "C" void kernel_launch(void* const* d_in, const int* in_sizes, int n_in,
                              void* d_out, int out_size, void* d_ws, size_t ws_size,
                              hipStream_t stream)
{
    const float* trg   = (const float*)d_in[0];
    const float* src   = (const float*)d_in[1];
    const int*   ei    = (const int*)d_in[2];
    const float* Wt    = (const float*)d_in[3];
    const float* Ws    = (const float*)d_in[4];
    const float* a_src = (const float*)d_in[5];
    const float* a_trg = (const float*)d_in[6];
    float* out = (float*)d_out;

    // workspace layout
    unsigned int* src_proj = (unsigned int*)d_ws;              // 3,200,000 u32 (bf16x2)
    float* ssrc      = (float*)(src_proj + (size_t)NNODE * 64);//   200,000 f
    float* strg      = ssrc + NNODE * NHH;                     //   200,000 f
    int*   counts    = (int*)(strg + NNODE * NHH);             //    50,000 i
    int*   offsets   = counts + NNODE;                         //    50,000 i
    int*   cursor    = offsets + NNODE;                        //    50,000 i
    int*   bsum      = cursor + NNODE;                         //       256 i
    int*   bofs      = bsum + 256;                             //       256 i
    int*   sorted_si = bofs + 256;                             //   800,000 i

    hipMemsetAsync(counts, 0, NNODE * sizeof(int), stream);

    // trg projection + degree-count tail
    proj2_kernel<0><<<NTILE, 256, 0, stream>>>(trg, Wt, a_trg, nullptr, strg,
                                               ei, counts, nullptr);
    scan_a_kernel<<<NB_SCAN, 256, 0, stream>>>(counts, offsets, bsum);
    scan_b_kernel<<<1, 256, 0, stream>>>(bsum, bofs);
    scan_c_kernel<<<NB_SCAN, 256, 0, stream>>>(offsets, bofs, cursor);
    // src projection (bf16 store) + CSR-scatter tail
    proj2_kernel<1><<<NTILE, 256, 0, stream>>>(src, Ws, a_src, src_proj, ssrc,
                                               ei, cursor, sorted_si);
    aggregate_gather_kernel<<<(NNODE + 3) / 4, 256, 0, stream>>>(offsets, counts, sorted_si,
                                                                 ssrc, strg, src_proj, out);
}

// Round 5
// 256.861 us; speedup vs baseline: 6.9327x; 1.1243x over previous
//
#include <hip/hip_runtime.h>
#include <hip/hip_fp16.h>
#include <math.h>

#define FIN   128
#define NHH   4
#define NNODE 50000
#define NEDGE 800000
#define NB_SCAN 196    // ceil(50000/256)
#define NTILE 782      // ceil(50000/64)
#define XROW  136      // 128 k + 8 pad (halves); row stride 272B -> 2-way (free)

typedef _Float16 half8   __attribute__((ext_vector_type(8)));
typedef float    floatx4 __attribute__((ext_vector_type(4)));

__device__ __forceinline__ float lrelu(float x) { return x > 0.f ? x : 0.2f * x; }

// ---------------------------------------------------------------------------
// W pre-convert: f32 W[k][c] -> f16 fragment-tiled for mfma_f32_16x16x32_f16
// B-frag layout: element (w,t,s,lane,j) = W[s*32+(lane>>4)*8+j][w*32+t*16+(lane&15)]
// flat index: (((w*2+t)*4+s)*64 + lane)*8 + j.  Block 0 -> Wt, block 1 -> Ws.
// ---------------------------------------------------------------------------
__global__ __launch_bounds__(256)
void wconv_kernel(const float* __restrict__ Wt, const float* __restrict__ Ws,
                  __half* __restrict__ out)
{
    const float* W = blockIdx.x ? Ws : Wt;
    __half* o = out + (size_t)blockIdx.x * 16384;
    for (int fr = threadIdx.x; fr < 2048; fr += 256) {
        const int l = fr & 63;
        const int s = (fr >> 6) & 3;
        const int t = (fr >> 8) & 1;
        const int w = fr >> 9;
        const int c  = w * 32 + t * 16 + (l & 15);
        const int k0 = s * 32 + (l >> 4) * 8;
        __half tmp[8];
        #pragma unroll
        for (int j = 0; j < 8; ++j)
            tmp[j] = __float2half_rn(W[(k0 + j) * 128 + c]);
        *(uint4*)(o + (size_t)fr * 8) = *(uint4*)tmp;
    }
}

// ---------------------------------------------------------------------------
// MFMA f16 projection + fused f32 score.
// Block = 64 nodes, wave w = head w (channels [32w,32w+32)).
// A = X tile (f16, LDS), B = frag-tiled Wf16 (global, L2-broadcast).
// D layout: channel n = lane&15 (+16t), node = m4*16 + (lane>>4)*4 + reg.
// STORE: src_proj packed f16x2, dword d=w*16+n holds channels (32w+n, 32w+16+n).
// ---------------------------------------------------------------------------
template<int STORE>
__global__ __launch_bounds__(256)
void proj3_kernel(const float* __restrict__ X, const __half* __restrict__ Wf,
                  const float* __restrict__ a, unsigned int* __restrict__ proj_pk,
                  float* __restrict__ scores)
{
    __shared__ __align__(16) __half xl[64 * XROW];
    const int tid  = threadIdx.x;
    const int lane = tid & 63;
    const int w    = __builtin_amdgcn_readfirstlane(tid >> 6);
    const int n0   = blockIdx.x * 64;

    // stage X -> f16 LDS: thread t handles node=t>>2, k-range (t&3)*32..+32
    {
        const int row = tid >> 2;
        const int kq  = (tid & 3) * 32;
        const float4* X4 = (const float4*)X;
        __half2* dst = (__half2*)(xl + row * XROW + kq);
        #pragma unroll
        for (int q = 0; q < 8; ++q) {
            float4 v = make_float4(0.f, 0.f, 0.f, 0.f);
            if (n0 + row < NNODE) v = X4[(size_t)(n0 + row) * 32 + (tid & 3) * 8 + q];
            dst[q * 2 + 0] = __halves2half2(__float2half_rn(v.x), __float2half_rn(v.y));
            dst[q * 2 + 1] = __halves2half2(__float2half_rn(v.z), __float2half_rn(v.w));
        }
    }
    __syncthreads();

    // B fragments: 2 ntiles x 4 ksteps, 16B/lane each, coalesced from L2
    half8 bf[2][4];
    {
        const uint4* Bp = (const uint4*)Wf;
        #pragma unroll
        for (int t = 0; t < 2; ++t)
            #pragma unroll
            for (int s = 0; s < 4; ++s) {
                uint4 u = Bp[((size_t)((w * 2 + t) * 4 + s)) * 64 + lane];
                bf[t][s] = *(half8*)&u;
            }
    }

    floatx4 acc[4][2];
    #pragma unroll
    for (int m4 = 0; m4 < 4; ++m4) { acc[m4][0] = (floatx4)0.f; acc[m4][1] = (floatx4)0.f; }

    #pragma unroll
    for (int m4 = 0; m4 < 4; ++m4) {
        #pragma unroll
        for (int s = 0; s < 4; ++s) {
            const half8 af = *(const half8*)(xl + (m4 * 16 + (lane & 15)) * XROW
                                                + s * 32 + (lane >> 4) * 8);
            acc[m4][0] = __builtin_amdgcn_mfma_f32_16x16x32_f16(af, bf[0][s], acc[m4][0], 0, 0, 0);
            acc[m4][1] = __builtin_amdgcn_mfma_f32_16x16x32_f16(af, bf[1][s], acc[m4][1], 0, 0, 0);
        }
    }

    // scores (f32 from accumulators): per (m4,reg) reduce over 16 channels
    const float a0 = a[w * 32 + (lane & 15)];
    const float a1 = a[w * 32 + 16 + (lane & 15)];
    #pragma unroll
    for (int m4 = 0; m4 < 4; ++m4) {
        #pragma unroll
        for (int reg = 0; reg < 4; ++reg) {
            float v = acc[m4][0][reg] * a0 + acc[m4][1][reg] * a1;
            v += __shfl_xor(v, 1, 16);
            v += __shfl_xor(v, 2, 16);
            v += __shfl_xor(v, 4, 16);
            v += __shfl_xor(v, 8, 16);
            const int node = n0 + m4 * 16 + (lane >> 4) * 4 + reg;
            if ((lane & 15) == reg && node < NNODE)
                scores[node * NHH + w] = v;
        }
    }

    if (STORE) {
        #pragma unroll
        for (int m4 = 0; m4 < 4; ++m4)
            #pragma unroll
            for (int reg = 0; reg < 4; ++reg) {
                const int node = n0 + m4 * 16 + (lane >> 4) * 4 + reg;
                if (node < NNODE) {
                    const __half2 pk = __halves2half2(__float2half_rn(acc[m4][0][reg]),
                                                      __float2half_rn(acc[m4][1][reg]));
                    proj_pk[(size_t)node * 64 + w * 16 + (lane & 15)] = *(const unsigned int*)&pk;
                }
            }
    }
}

// ---------------------------------------------------------------------------
// Edge pass 1: degree histogram of targets.
// ---------------------------------------------------------------------------
__global__ __launch_bounds__(256)
void count_kernel(const int* __restrict__ ei, int* __restrict__ counts)
{
    const int e = blockIdx.x * 256 + threadIdx.x;
    if (e >= NEDGE) return;
    atomicAdd(counts + ei[NEDGE + e], 1);
}

// ---------------------------------------------------------------------------
// 3-kernel exclusive scan over counts -> offsets (+cursor copy)
// ---------------------------------------------------------------------------
__global__ __launch_bounds__(256)
void scan_a_kernel(const int* __restrict__ counts, int* __restrict__ offsets,
                   int* __restrict__ bsum)
{
    __shared__ int s[256];
    const int tid = threadIdx.x;
    const int i = blockIdx.x * 256 + tid;
    const int v = (i < NNODE) ? counts[i] : 0;
    s[tid] = v;
    __syncthreads();
    #pragma unroll
    for (int off = 1; off < 256; off <<= 1) {
        const int x = (tid >= off) ? s[tid - off] : 0;
        __syncthreads();
        s[tid] += x;
        __syncthreads();
    }
    if (i < NNODE) offsets[i] = s[tid] - v;
    if (tid == 255) bsum[blockIdx.x] = s[tid];
}

__global__ __launch_bounds__(256)
void scan_b_kernel(int* __restrict__ bsum, int* __restrict__ bofs)
{
    __shared__ int s[256];
    const int tid = threadIdx.x;
    const int v = (tid < NB_SCAN) ? bsum[tid] : 0;
    s[tid] = v;
    __syncthreads();
    #pragma unroll
    for (int off = 1; off < 256; off <<= 1) {
        const int x = (tid >= off) ? s[tid - off] : 0;
        __syncthreads();
        s[tid] += x;
        __syncthreads();
    }
    if (tid < NB_SCAN) bofs[tid] = s[tid] - v;
}

__global__ __launch_bounds__(256)
void scan_c_kernel(int* __restrict__ offsets, const int* __restrict__ bofs,
                   int* __restrict__ cursor)
{
    const int i = blockIdx.x * 256 + threadIdx.x;
    if (i < NNODE) {
        const int v = offsets[i] + bofs[blockIdx.x];
        offsets[i] = v;
        cursor[i]  = v;
    }
}

// ---------------------------------------------------------------------------
// Edge pass 2: CSR scatter of source ids by target.
// ---------------------------------------------------------------------------
__global__ __launch_bounds__(256)
void scatter_kernel(const int* __restrict__ ei, int* __restrict__ cursor,
                    int* __restrict__ sorted_si)
{
    const int e = blockIdx.x * 256 + threadIdx.x;
    if (e >= NEDGE) return;
    const int si = ei[e];
    const int ti = ei[NEDGE + e];
    const int p = atomicAdd(cursor + ti, 1);
    sorted_si[p] = si;
}

// ---------------------------------------------------------------------------
// Aggregate (gather): one wave per target; lane owns the f16x2 pair
// (channel 32w+n, 32w+16+n), w=lane>>4 (= head), n=lane&15.
// ---------------------------------------------------------------------------
__global__ __launch_bounds__(256)
void aggregate_gather_kernel(const int* __restrict__ offsets, const int* __restrict__ counts,
                             const int* __restrict__ sorted_si,
                             const float* __restrict__ ssrc, const float* __restrict__ strg,
                             const unsigned int* __restrict__ src_proj,
                             float* __restrict__ out)
{
    const int lane = threadIdx.x & 63;
    const int wv   = threadIdx.x >> 6;
    const int t = blockIdx.x * 4 + wv;
    if (t >= NNODE) return;
    const int h = lane >> 4;
    const float st = strg[t * NHH + h];
    const int start = offsets[t];
    const int end   = start + counts[t];

    float2 acc = make_float2(0.f, 0.f);
    float d = 0.f;
    int j = start;
    for (; j + 4 <= end; j += 4) {
        const int si0 = sorted_si[j + 0];
        const int si1 = sorted_si[j + 1];
        const int si2 = sorted_si[j + 2];
        const int si3 = sorted_si[j + 3];
        const float s0 = ssrc[si0 * NHH + h];
        const float s1 = ssrc[si1 * NHH + h];
        const float s2 = ssrc[si2 * NHH + h];
        const float s3 = ssrc[si3 * NHH + h];
        const unsigned int w0 = src_proj[(size_t)si0 * 64 + lane];
        const unsigned int w1 = src_proj[(size_t)si1 * 64 + lane];
        const unsigned int w2 = src_proj[(size_t)si2 * 64 + lane];
        const unsigned int w3 = src_proj[(size_t)si3 * 64 + lane];
        const float e0 = __expf(lrelu(s0 + st));
        const float e1 = __expf(lrelu(s1 + st));
        const float e2 = __expf(lrelu(s2 + st));
        const float e3 = __expf(lrelu(s3 + st));
        const __half2 h0 = *(const __half2*)&w0;
        const __half2 h1 = *(const __half2*)&w1;
        const __half2 h2 = *(const __half2*)&w2;
        const __half2 h3 = *(const __half2*)&w3;
        acc.x = fmaf(__low2float(h0),  e0, acc.x);
        acc.y = fmaf(__high2float(h0), e0, acc.y);
        acc.x = fmaf(__low2float(h1),  e1, acc.x);
        acc.y = fmaf(__high2float(h1), e1, acc.y);
        acc.x = fmaf(__low2float(h2),  e2, acc.x);
        acc.y = fmaf(__high2float(h2), e2, acc.y);
        acc.x = fmaf(__low2float(h3),  e3, acc.x);
        acc.y = fmaf(__high2float(h3), e3, acc.y);
        d += e0 + e1 + e2 + e3;
    }
    for (; j < end; ++j) {
        const int si = sorted_si[j];
        const float e = __expf(lrelu(ssrc[si * NHH + h] + st));
        const unsigned int wd = src_proj[(size_t)si * 64 + lane];
        const __half2 hv = *(const __half2*)&wd;
        acc.x = fmaf(__low2float(hv),  e, acc.x);
        acc.y = fmaf(__high2float(hv), e, acc.y);
        d += e;
    }
    const float inv = 1.0f / (d + 1e-16f);
    const int c1 = (lane >> 4) * 32 + (lane & 15);   // undo the in-row permutation
    out[(size_t)t * 128 + c1]      = acc.x * inv;
    out[(size_t)t * 128 + c1 + 16] = acc.y * inv;
}

// ---------------------------------------------------------------------------
extern "C" void kernel_launch(void* const* d_in, const int* in_sizes, int n_in,
                              void* d_out, int out_size, void* d_ws, size_t ws_size,
                              hipStream_t stream)
{
    const float* trg   = (const float*)d_in[0];
    const float* src   = (const float*)d_in[1];
    const int*   ei    = (const int*)d_in[2];
    const float* Wt    = (const float*)d_in[3];
    const float* Ws    = (const float*)d_in[4];
    const float* a_src = (const float*)d_in[5];
    const float* a_trg = (const float*)d_in[6];
    float* out = (float*)d_out;

    // workspace layout (all offsets 16B-aligned)
    unsigned int* src_proj = (unsigned int*)d_ws;               // 3,200,000 u32
    float* ssrc      = (float*)(src_proj + (size_t)NNODE * 64); //   200,000 f
    float* strg      = ssrc + NNODE * NHH;                      //   200,000 f
    int*   counts    = (int*)(strg + NNODE * NHH);              //    50,000 i
    int*   offsets   = counts + NNODE;                          //    50,000 i
    int*   cursor    = offsets + NNODE;                         //    50,000 i
    int*   bsum      = cursor + NNODE;                          //       256 i
    int*   bofs      = bsum + 256;                              //       256 i
    int*   sorted_si = bofs + 256;                              //   800,000 i
    __half* wf16     = (__half*)(sorted_si + NEDGE);            //    32,768 h (Wt|Ws tiled)

    hipMemsetAsync(counts, 0, NNODE * sizeof(int), stream);
    wconv_kernel<<<2, 256, 0, stream>>>(Wt, Ws, wf16);

    proj3_kernel<0><<<NTILE, 256, 0, stream>>>(trg, wf16,         a_trg, nullptr,  strg);
    count_kernel<<<(NEDGE + 255) / 256, 256, 0, stream>>>(ei, counts);
    scan_a_kernel<<<NB_SCAN, 256, 0, stream>>>(counts, offsets, bsum);
    scan_b_kernel<<<1, 256, 0, stream>>>(bsum, bofs);
    scan_c_kernel<<<NB_SCAN, 256, 0, stream>>>(offsets, bofs, cursor);
    proj3_kernel<1><<<NTILE, 256, 0, stream>>>(src, wf16 + 16384, a_src, src_proj, ssrc);
    scatter_kernel<<<(NEDGE + 255) / 256, 256, 0, stream>>>(ei, cursor, sorted_si);
    aggregate_gather_kernel<<<(NNODE + 3) / 4, 256, 0, stream>>>(offsets, counts, sorted_si,
                                                                 ssrc, strg, src_proj, out);
}

// Round 6
// 237.337 us; speedup vs baseline: 7.5030x; 1.0823x over previous
//
#include <hip/hip_runtime.h>
#include <hip/hip_fp16.h>
#include <math.h>

#define FIN   128
#define NHH   4
#define NNODE 50000
#define NEDGE 800000
#define NB_SCAN 196     // ceil(50000/256)
#define NTILE 782       // ceil(50000/64)
#define NEBLK 3125      // NEDGE/256
#define XROW  136       // 128 k + 8 pad (halves)

typedef _Float16 half8   __attribute__((ext_vector_type(8)));
typedef float    floatx4 __attribute__((ext_vector_type(4)));

__device__ __forceinline__ float lrelu(float x) { return x > 0.f ? x : 0.2f * x; }

// ---------------------------------------------------------------------------
// K0: blocks 0,1 convert Wt/Ws -> f16 fragment-tiled; blocks >=2 do the
// target-degree histogram. Independent work, co-resident.
// B-frag layout: element (w,t,s,lane,j) = W[s*32+(lane>>4)*8+j][w*32+t*16+(lane&15)]
// ---------------------------------------------------------------------------
__global__ __launch_bounds__(256)
void prep_kernel(const float* __restrict__ Wt, const float* __restrict__ Ws,
                 __half* __restrict__ wf16, const int* __restrict__ ei,
                 int* __restrict__ counts)
{
    const int b = blockIdx.x;
    if (b < 2) {
        const float* W = b ? Ws : Wt;
        __half* o = wf16 + (size_t)b * 16384;
        for (int fr = threadIdx.x; fr < 2048; fr += 256) {
            const int l = fr & 63;
            const int s = (fr >> 6) & 3;
            const int t = (fr >> 8) & 1;
            const int w = fr >> 9;
            const int c  = w * 32 + t * 16 + (l & 15);
            const int k0 = s * 32 + (l >> 4) * 8;
            __half tmp[8];
            #pragma unroll
            for (int j = 0; j < 8; ++j)
                tmp[j] = __float2half_rn(W[(k0 + j) * 128 + c]);
            *(uint4*)(o + (size_t)fr * 8) = *(uint4*)tmp;
        }
    } else {
        const int e = (b - 2) * 256 + threadIdx.x;
        if (e < NEDGE) atomicAdd(counts + ei[NEDGE + e], 1);
    }
}

// ---------------------------------------------------------------------------
// MFMA f16 projection body (as round 5): block bb = 64 nodes, wave w = head w.
// ---------------------------------------------------------------------------
template<int STORE>
__device__ __forceinline__
void proj_body(int bb, const float* __restrict__ X, const __half* __restrict__ Wf,
               const float* __restrict__ a, unsigned int* __restrict__ proj_pk,
               float* __restrict__ scores, __half* xl)
{
    const int tid  = threadIdx.x;
    const int lane = tid & 63;
    const int w    = __builtin_amdgcn_readfirstlane(tid >> 6);
    const int n0   = bb * 64;

    {
        const int row = tid >> 2;
        const float4* X4 = (const float4*)X;
        __half2* dst = (__half2*)(xl + row * XROW + (tid & 3) * 32);
        #pragma unroll
        for (int q = 0; q < 8; ++q) {
            float4 v = make_float4(0.f, 0.f, 0.f, 0.f);
            if (n0 + row < NNODE) v = X4[(size_t)(n0 + row) * 32 + (tid & 3) * 8 + q];
            dst[q * 2 + 0] = __halves2half2(__float2half_rn(v.x), __float2half_rn(v.y));
            dst[q * 2 + 1] = __halves2half2(__float2half_rn(v.z), __float2half_rn(v.w));
        }
    }
    __syncthreads();

    half8 bf[2][4];
    {
        const uint4* Bp = (const uint4*)Wf;
        #pragma unroll
        for (int t = 0; t < 2; ++t)
            #pragma unroll
            for (int s = 0; s < 4; ++s) {
                uint4 u = Bp[((size_t)((w * 2 + t) * 4 + s)) * 64 + lane];
                bf[t][s] = *(half8*)&u;
            }
    }

    floatx4 acc[4][2];
    #pragma unroll
    for (int m4 = 0; m4 < 4; ++m4) { acc[m4][0] = (floatx4)0.f; acc[m4][1] = (floatx4)0.f; }

    #pragma unroll
    for (int m4 = 0; m4 < 4; ++m4) {
        #pragma unroll
        for (int s = 0; s < 4; ++s) {
            const half8 af = *(const half8*)(xl + (m4 * 16 + (lane & 15)) * XROW
                                                + s * 32 + (lane >> 4) * 8);
            acc[m4][0] = __builtin_amdgcn_mfma_f32_16x16x32_f16(af, bf[0][s], acc[m4][0], 0, 0, 0);
            acc[m4][1] = __builtin_amdgcn_mfma_f32_16x16x32_f16(af, bf[1][s], acc[m4][1], 0, 0, 0);
        }
    }

    const float a0 = a[w * 32 + (lane & 15)];
    const float a1 = a[w * 32 + 16 + (lane & 15)];
    #pragma unroll
    for (int m4 = 0; m4 < 4; ++m4) {
        #pragma unroll
        for (int reg = 0; reg < 4; ++reg) {
            float v = acc[m4][0][reg] * a0 + acc[m4][1][reg] * a1;
            v += __shfl_xor(v, 1, 16);
            v += __shfl_xor(v, 2, 16);
            v += __shfl_xor(v, 4, 16);
            v += __shfl_xor(v, 8, 16);
            const int node = n0 + m4 * 16 + (lane >> 4) * 4 + reg;
            if ((lane & 15) == reg && node < NNODE)
                scores[node * NHH + w] = v;
        }
    }

    if (STORE) {
        #pragma unroll
        for (int m4 = 0; m4 < 4; ++m4)
            #pragma unroll
            for (int reg = 0; reg < 4; ++reg) {
                const int node = n0 + m4 * 16 + (lane >> 4) * 4 + reg;
                if (node < NNODE) {
                    const __half2 pk = __halves2half2(__float2half_rn(acc[m4][0][reg]),
                                                      __float2half_rn(acc[m4][1][reg]));
                    proj_pk[(size_t)node * 64 + w * 16 + (lane & 15)] = *(const unsigned int*)&pk;
                }
            }
    }
}

// ---------------------------------------------------------------------------
// K4: blocks [0,NEBLK) = CSR scatter (short-lived, dispatched first);
//     blocks [NEBLK, NEBLK+NTILE) = trg projection;
//     blocks [NEBLK+NTILE, ...)  = src projection (+proj store).
// Scatter's latency-bound waves co-schedule under proj's MFMA waves (m114).
// ---------------------------------------------------------------------------
__global__ __launch_bounds__(256)
void main_fused_kernel(const float* __restrict__ trg, const float* __restrict__ src,
                       const int* __restrict__ ei, const __half* __restrict__ wf16,
                       const float* __restrict__ a_trg, const float* __restrict__ a_src,
                       float* __restrict__ strg, float* __restrict__ ssrc,
                       unsigned int* __restrict__ src_proj,
                       int* __restrict__ cursor, int* __restrict__ sorted_si)
{
    __shared__ __align__(16) __half xl[64 * XROW];
    const int b = blockIdx.x;
    if (b < NEBLK) {
        const int e = b * 256 + threadIdx.x;
        if (e < NEDGE) {
            const int si = ei[e];
            const int ti = ei[NEDGE + e];
            const int p = atomicAdd(cursor + ti, 1);
            sorted_si[p] = si;
        }
    } else if (b < NEBLK + NTILE) {
        proj_body<0>(b - NEBLK, trg, wf16, a_trg, nullptr, strg, xl);
    } else {
        proj_body<1>(b - NEBLK - NTILE, src, wf16 + 16384, a_src, src_proj, ssrc, xl);
    }
}

// ---------------------------------------------------------------------------
// 3-kernel exclusive scan over counts -> offsets (+cursor copy)
// ---------------------------------------------------------------------------
__global__ __launch_bounds__(256)
void scan_a_kernel(const int* __restrict__ counts, int* __restrict__ offsets,
                   int* __restrict__ bsum)
{
    __shared__ int s[256];
    const int tid = threadIdx.x;
    const int i = blockIdx.x * 256 + tid;
    const int v = (i < NNODE) ? counts[i] : 0;
    s[tid] = v;
    __syncthreads();
    #pragma unroll
    for (int off = 1; off < 256; off <<= 1) {
        const int x = (tid >= off) ? s[tid - off] : 0;
        __syncthreads();
        s[tid] += x;
        __syncthreads();
    }
    if (i < NNODE) offsets[i] = s[tid] - v;
    if (tid == 255) bsum[blockIdx.x] = s[tid];
}

__global__ __launch_bounds__(256)
void scan_b_kernel(int* __restrict__ bsum, int* __restrict__ bofs)
{
    __shared__ int s[256];
    const int tid = threadIdx.x;
    const int v = (tid < NB_SCAN) ? bsum[tid] : 0;
    s[tid] = v;
    __syncthreads();
    #pragma unroll
    for (int off = 1; off < 256; off <<= 1) {
        const int x = (tid >= off) ? s[tid - off] : 0;
        __syncthreads();
        s[tid] += x;
        __syncthreads();
    }
    if (tid < NB_SCAN) bofs[tid] = s[tid] - v;
}

__global__ __launch_bounds__(256)
void scan_c_kernel(int* __restrict__ offsets, const int* __restrict__ bofs,
                   int* __restrict__ cursor)
{
    const int i = blockIdx.x * 256 + threadIdx.x;
    if (i < NNODE) {
        const int v = offsets[i] + bofs[blockIdx.x];
        offsets[i] = v;
        cursor[i]  = v;
    }
}

// ---------------------------------------------------------------------------
// Aggregate (gather): one wave per target; lane owns the f16x2 pair
// (channel 32w+n, 32w+16+n), w=lane>>4 (= head), n=lane&15.
// ---------------------------------------------------------------------------
__global__ __launch_bounds__(256)
void aggregate_gather_kernel(const int* __restrict__ offsets, const int* __restrict__ counts,
                             const int* __restrict__ sorted_si,
                             const float* __restrict__ ssrc, const float* __restrict__ strg,
                             const unsigned int* __restrict__ src_proj,
                             float* __restrict__ out)
{
    const int lane = threadIdx.x & 63;
    const int wv   = threadIdx.x >> 6;
    const int t = blockIdx.x * 4 + wv;
    if (t >= NNODE) return;
    const int h = lane >> 4;
    const float st = strg[t * NHH + h];
    const int start = offsets[t];
    const int end   = start + counts[t];

    float2 acc = make_float2(0.f, 0.f);
    float d = 0.f;
    int j = start;
    for (; j + 4 <= end; j += 4) {
        const int si0 = sorted_si[j + 0];
        const int si1 = sorted_si[j + 1];
        const int si2 = sorted_si[j + 2];
        const int si3 = sorted_si[j + 3];
        const float s0 = ssrc[si0 * NHH + h];
        const float s1 = ssrc[si1 * NHH + h];
        const float s2 = ssrc[si2 * NHH + h];
        const float s3 = ssrc[si3 * NHH + h];
        const unsigned int w0 = src_proj[(size_t)si0 * 64 + lane];
        const unsigned int w1 = src_proj[(size_t)si1 * 64 + lane];
        const unsigned int w2 = src_proj[(size_t)si2 * 64 + lane];
        const unsigned int w3 = src_proj[(size_t)si3 * 64 + lane];
        const float e0 = __expf(lrelu(s0 + st));
        const float e1 = __expf(lrelu(s1 + st));
        const float e2 = __expf(lrelu(s2 + st));
        const float e3 = __expf(lrelu(s3 + st));
        const __half2 h0 = *(const __half2*)&w0;
        const __half2 h1 = *(const __half2*)&w1;
        const __half2 h2 = *(const __half2*)&w2;
        const __half2 h3 = *(const __half2*)&w3;
        acc.x = fmaf(__low2float(h0),  e0, acc.x);
        acc.y = fmaf(__high2float(h0), e0, acc.y);
        acc.x = fmaf(__low2float(h1),  e1, acc.x);
        acc.y = fmaf(__high2float(h1), e1, acc.y);
        acc.x = fmaf(__low2float(h2),  e2, acc.x);
        acc.y = fmaf(__high2float(h2), e2, acc.y);
        acc.x = fmaf(__low2float(h3),  e3, acc.x);
        acc.y = fmaf(__high2float(h3), e3, acc.y);
        d += e0 + e1 + e2 + e3;
    }
    for (; j < end; ++j) {
        const int si = sorted_si[j];
        const float e = __expf(lrelu(ssrc[si * NHH + h] + st));
        const unsigned int wd = src_proj[(size_t)si * 64 + lane];
        const __half2 hv = *(const __half2*)&wd;
        acc.x = fmaf(__low2float(hv),  e, acc.x);
        acc.y = fmaf(__high2float(hv), e, acc.y);
        d += e;
    }
    const float inv = 1.0f / (d + 1e-16f);
    const int c1 = (lane >> 4) * 32 + (lane & 15);
    out[(size_t)t * 128 + c1]      = acc.x * inv;
    out[(size_t)t * 128 + c1 + 16] = acc.y * inv;
}

// ---------------------------------------------------------------------------
extern "C" void kernel_launch(void* const* d_in, const int* in_sizes, int n_in,
                              void* d_out, int out_size, void* d_ws, size_t ws_size,
                              hipStream_t stream)
{
    const float* trg   = (const float*)d_in[0];
    const float* src   = (const float*)d_in[1];
    const int*   ei    = (const int*)d_in[2];
    const float* Wt    = (const float*)d_in[3];
    const float* Ws    = (const float*)d_in[4];
    const float* a_src = (const float*)d_in[5];
    const float* a_trg = (const float*)d_in[6];
    float* out = (float*)d_out;

    // workspace layout (all offsets 16B-aligned)
    unsigned int* src_proj = (unsigned int*)d_ws;               // 3,200,000 u32
    float* ssrc      = (float*)(src_proj + (size_t)NNODE * 64); //   200,000 f
    float* strg      = ssrc + NNODE * NHH;                      //   200,000 f
    int*   counts    = (int*)(strg + NNODE * NHH);              //    50,000 i
    int*   offsets   = counts + NNODE;                          //    50,000 i
    int*   cursor    = offsets + NNODE;                         //    50,000 i
    int*   bsum      = cursor + NNODE;                          //       256 i
    int*   bofs      = bsum + 256;                              //       256 i
    int*   sorted_si = bofs + 256;                              //   800,000 i
    __half* wf16     = (__half*)(sorted_si + NEDGE);            //    32,768 h

    hipMemsetAsync(counts, 0, NNODE * sizeof(int), stream);

    prep_kernel<<<2 + NEBLK, 256, 0, stream>>>(Wt, Ws, wf16, ei, counts);
    scan_a_kernel<<<NB_SCAN, 256, 0, stream>>>(counts, offsets, bsum);
    scan_b_kernel<<<1, 256, 0, stream>>>(bsum, bofs);
    scan_c_kernel<<<NB_SCAN, 256, 0, stream>>>(offsets, bofs, cursor);
    main_fused_kernel<<<NEBLK + 2 * NTILE, 256, 0, stream>>>(trg, src, ei, wf16,
                                                             a_trg, a_src, strg, ssrc,
                                                             src_proj, cursor, sorted_si);
    aggregate_gather_kernel<<<(NNODE + 3) / 4, 256, 0, stream>>>(offsets, counts, sorted_si,
                                                                 ssrc, strg, src_proj, out);
}